// Round 1
// baseline (1353.986 us; speedup 1.0000x reference)
//
#include <hip/hip_runtime.h>
#include <hip/hip_bf16.h>
#include <stdint.h>

#define BB 2
#define SS 2048
#define DD 2048
#define HH 16
#define HD 128
#define FFD 8192
#define TD (3*DD)

typedef unsigned short u16;
typedef __attribute__((ext_vector_type(8))) short s16x8;
typedef __attribute__((ext_vector_type(4))) float f32x4;

struct alignas(8) U16x4 { u16 a, b, c, d; };

__device__ __forceinline__ u16 f2b(float f) {
  union { float f; uint32_t u; } v; v.f = f;
  uint32_t r = (v.u + 0x7fffu + ((v.u >> 16) & 1u)) >> 16;
  return (u16)r;
}

__device__ __forceinline__ void async16(const void* g, void* l) {
  __builtin_amdgcn_global_load_lds((const __attribute__((address_space(1))) void*)g,
                                   (__attribute__((address_space(3))) void*)l,
                                   16, 0, 0);
}

// ---------------- fused fp32->bf16 transpose-convert:  Wt[N][K] = bf16(W[K][N]) ---
__global__ __launch_bounds__(256) void wconv_t(const float* __restrict__ W,
                                               u16* __restrict__ Wt, int K, int N) {
  __shared__ float tile[64][65];
  int k0 = blockIdx.x * 64, n0 = blockIdx.y * 64;
  int c = threadIdx.x & 63, r0 = threadIdx.x >> 6;
#pragma unroll
  for (int i = 0; i < 16; ++i) {
    int r = i * 4 + r0;
    tile[r][c] = W[(size_t)(k0 + r) * N + n0 + c];
  }
  __syncthreads();
#pragma unroll
  for (int i = 0; i < 16; ++i) {
    int n = i * 4 + r0;
    Wt[(size_t)(n0 + n) * K + k0 + c] = f2b(tile[c][n]);
  }
}

// ---------------- layernorm: fp32 in -> bf16 out, one block per row (D=2048) ------
__global__ __launch_bounds__(256) void ln_kernel(const float* __restrict__ X,
                                                 const float* __restrict__ g,
                                                 const float* __restrict__ be,
                                                 u16* __restrict__ O) {
  int row = blockIdx.x;
  const float* xr = X + (size_t)row * DD;
  int t = threadIdx.x;
  float4 v0 = ((const float4*)xr)[t];
  float4 v1 = ((const float4*)xr)[t + 256];
  float s = v0.x + v0.y + v0.z + v0.w + v1.x + v1.y + v1.z + v1.w;
  float q = v0.x*v0.x + v0.y*v0.y + v0.z*v0.z + v0.w*v0.w
          + v1.x*v1.x + v1.y*v1.y + v1.z*v1.z + v1.w*v1.w;
#pragma unroll
  for (int o = 32; o > 0; o >>= 1) { s += __shfl_down(s, o); q += __shfl_down(q, o); }
  __shared__ float red[8];
  if ((t & 63) == 0) { red[t >> 6] = s; red[4 + (t >> 6)] = q; }
  __syncthreads();
  float S = red[0] + red[1] + red[2] + red[3];
  float Q = red[4] + red[5] + red[6] + red[7];
  float mu = S * (1.0f / DD);
  float var = Q * (1.0f / DD) - mu * mu;
  float rs = rsqrtf(var + 1e-5f);
  float4 g0 = ((const float4*)g)[t],  g1 = ((const float4*)g)[t + 256];
  float4 b0 = ((const float4*)be)[t], b1 = ((const float4*)be)[t + 256];
  U16x4 o0, o1;
  o0.a = f2b((v0.x - mu) * rs * g0.x + b0.x);
  o0.b = f2b((v0.y - mu) * rs * g0.y + b0.y);
  o0.c = f2b((v0.z - mu) * rs * g0.z + b0.z);
  o0.d = f2b((v0.w - mu) * rs * g0.w + b0.w);
  o1.a = f2b((v1.x - mu) * rs * g1.x + b1.x);
  o1.b = f2b((v1.y - mu) * rs * g1.y + b1.y);
  o1.c = f2b((v1.z - mu) * rs * g1.z + b1.z);
  o1.d = f2b((v1.w - mu) * rs * g1.w + b1.w);
  *(U16x4*)(O + (size_t)row * DD + t * 4)         = o0;
  *(U16x4*)(O + (size_t)row * DD + (t + 256) * 4) = o1;
}

// ---------------- GEMM: C[M,N] = A[M,K](bf16) * Bt[N,K](bf16)^T + bias (+epilogue) -
// MODE 0: +bias -> bf16 ; MODE 1: +bias,gelu -> bf16 ; MODE 2: +bias,+res -> fp32
template <int MODE>
__global__ __launch_bounds__(256) void gemm_bt(const u16* __restrict__ A,
                                               const u16* __restrict__ Bt,
                                               const float* __restrict__ bias,
                                               const float* __restrict__ res,
                                               void* __restrict__ Cout,
                                               int M, int N, int K) {
  __shared__ __align__(16) u16 As[128 * 64];
  __shared__ __align__(16) u16 Bs[128 * 64];
  int n0 = blockIdx.x * 128, m0 = blockIdx.y * 128;
  int tid = threadIdx.x;
  int lane = tid & 63, w = tid >> 6;
  int wm = w >> 1, wn = w & 1;
  int col = lane & 15, quad = lane >> 4;
  f32x4 acc[4][4] = {};
  const u16* ag = A  + (size_t)(m0 + (tid >> 3)) * K + (tid & 7) * 8;
  const u16* bg = Bt + (size_t)(n0 + (tid >> 3)) * K + (tid & 7) * 8;
  for (int k0 = 0; k0 < K; k0 += 64) {
    __syncthreads();
#pragma unroll
    for (int s = 0; s < 4; ++s) {
      async16(ag + (size_t)s * 32 * K + k0, &As[s * 2048 + tid * 8]);
      async16(bg + (size_t)s * 32 * K + k0, &Bs[s * 2048 + tid * 8]);
    }
    __syncthreads();
#pragma unroll
    for (int kk = 0; kk < 64; kk += 32) {
      s16x8 af[4], bf[4];
#pragma unroll
      for (int mt = 0; mt < 4; ++mt)
        af[mt] = *(const s16x8*)&As[(wm * 64 + mt * 16 + col) * 64 + kk + quad * 8];
#pragma unroll
      for (int nt = 0; nt < 4; ++nt)
        bf[nt] = *(const s16x8*)&Bs[(wn * 64 + nt * 16 + col) * 64 + kk + quad * 8];
#pragma unroll
      for (int mt = 0; mt < 4; ++mt)
#pragma unroll
        for (int nt = 0; nt < 4; ++nt)
          acc[mt][nt] = __builtin_amdgcn_mfma_f32_16x16x32_bf16(af[mt], bf[nt], acc[mt][nt], 0, 0, 0);
    }
  }
#pragma unroll
  for (int mt = 0; mt < 4; ++mt) {
    int mg = m0 + wm * 64 + mt * 16 + quad * 4;
#pragma unroll
    for (int nt = 0; nt < 4; ++nt) {
      int ng = n0 + wn * 64 + nt * 16 + col;
      float bn = bias[ng];
#pragma unroll
      for (int r = 0; r < 4; ++r) {
        float v = acc[mt][nt][r] + bn;
        size_t idx = (size_t)(mg + r) * N + ng;
        if (MODE == 1) {
          float u = 0.7978845608028654f * (v + 0.044715f * v * v * v);
          v = 0.5f * v * (1.0f + tanhf(u));
        }
        if (MODE == 2) {
          ((float*)Cout)[idx] = v + res[idx];
        } else {
          ((u16*)Cout)[idx] = f2b(v);
        }
      }
    }
  }
}

// ---------------- flash attention with ALiBi + causal --------------------------
// grid: (S/64, H, B); block 256 (4 waves); wave w owns q rows q0+16w..+15
__global__ __launch_bounds__(256) void attn_kernel(const u16* __restrict__ qkv,
                                                   u16* __restrict__ out) {
  __shared__ __align__(16) u16 Ks[64 * 128];
  __shared__ __align__(16) u16 Vts[128 * 64];
  __shared__ __align__(16) u16 Ps[4][16 * 64];
  int qt = blockIdx.x, h = blockIdx.y, b = blockIdx.z;
  int q0 = qt * 64;
  int tid = threadIdx.x, lane = tid & 63, w = tid >> 6;
  int col = lane & 15, quad = lane >> 4;
  const u16* base  = qkv + (size_t)b * SS * TD + (size_t)h * HD;
  const u16* kbase = base + DD;
  const u16* vbase = base + 2 * DD;
  int qr = q0 + w * 16 + col;   // A-layout: m = lane&15
  s16x8 qf[4];
#pragma unroll
  for (int c = 0; c < 4; ++c)
    qf[c] = *(const s16x8*)(base + (size_t)qr * TD + c * 32 + quad * 8);
  float m_i[4] = {-1e30f, -1e30f, -1e30f, -1e30f};
  float l_i[4] = {0.f, 0.f, 0.f, 0.f};
  f32x4 oacc[8] = {};
  float slope = exp2f(-0.5f * (float)(h + 1));
  const float scale = 0.088388347648318447f;  // 1/sqrt(128)
  int ntile = qt + 1;
  for (int t = 0; t < ntile; ++t) {
    int j0 = t * 64;
    __syncthreads();
#pragma unroll
    for (int s = 0; s < 4; ++s)
      async16(kbase + (size_t)(j0 + s * 16 + (tid >> 4)) * TD + (tid & 15) * 8,
              &Ks[s * 2048 + tid * 8]);
#pragma unroll
    for (int s = 0; s < 4; ++s) {
      int key = s * 16 + (tid >> 4);
      int hd0 = (tid & 15) * 8;
      s16x8 vv = *(const s16x8*)(vbase + (size_t)(j0 + key) * TD + hd0);
#pragma unroll
      for (int j = 0; j < 8; ++j) Vts[(hd0 + j) * 64 + key] = (u16)vv[j];
    }
    __syncthreads();
    f32x4 sc[4];
#pragma unroll
    for (int nt = 0; nt < 4; ++nt) {
      f32x4 s4 = {0.f, 0.f, 0.f, 0.f};
      int key = nt * 16 + col;
#pragma unroll
      for (int c = 0; c < 4; ++c) {
        s16x8 kf = *(const s16x8*)&Ks[key * 128 + c * 32 + quad * 8];
        s4 = __builtin_amdgcn_mfma_f32_16x16x32_bf16(qf[c], kf, s4, 0, 0, 0);
      }
      sc[nt] = s4;
    }
    int rb = q0 + w * 16 + quad * 4;
    float p[4][4];
    float mt_[4] = {-1e30f, -1e30f, -1e30f, -1e30f};
#pragma unroll
    for (int nt = 0; nt < 4; ++nt) {
      int j = j0 + nt * 16 + col;
#pragma unroll
      for (int r = 0; r < 4; ++r) {
        float v = sc[nt][r] * scale + slope * (float)(j - (rb + r));
        if (j > rb + r) v = -1e30f;
        p[nt][r] = v;
        mt_[r] = fmaxf(mt_[r], v);
      }
    }
#pragma unroll
    for (int o = 1; o < 16; o <<= 1)
#pragma unroll
      for (int r = 0; r < 4; ++r) mt_[r] = fmaxf(mt_[r], __shfl_xor(mt_[r], o));
    float alpha[4];
#pragma unroll
    for (int r = 0; r < 4; ++r) {
      float mn = fmaxf(m_i[r], mt_[r]);
      alpha[r] = __expf(m_i[r] - mn);
      m_i[r] = mn;
    }
    float ls[4] = {0.f, 0.f, 0.f, 0.f};
#pragma unroll
    for (int nt = 0; nt < 4; ++nt)
#pragma unroll
      for (int r = 0; r < 4; ++r) {
        float e = __expf(p[nt][r] - m_i[r]);
        p[nt][r] = e;
        ls[r] += e;
      }
#pragma unroll
    for (int o = 1; o < 16; o <<= 1)
#pragma unroll
      for (int r = 0; r < 4; ++r) ls[r] += __shfl_xor(ls[r], o);
#pragma unroll
    for (int r = 0; r < 4; ++r) l_i[r] = l_i[r] * alpha[r] + ls[r];
#pragma unroll
    for (int ot = 0; ot < 8; ++ot)
#pragma unroll
      for (int r = 0; r < 4; ++r) oacc[ot][r] *= alpha[r];
#pragma unroll
    for (int nt = 0; nt < 4; ++nt)
#pragma unroll
      for (int r = 0; r < 4; ++r)
        Ps[w][(quad * 4 + r) * 64 + nt * 16 + col] = f2b(p[nt][r]);
    __syncthreads();
#pragma unroll
    for (int kt = 0; kt < 2; ++kt) {
      s16x8 pf = *(const s16x8*)&Ps[w][col * 64 + kt * 32 + quad * 8];
#pragma unroll
      for (int ot = 0; ot < 8; ++ot) {
        s16x8 vf = *(const s16x8*)&Vts[(ot * 16 + col) * 64 + kt * 32 + quad * 8];
        oacc[ot] = __builtin_amdgcn_mfma_f32_16x16x32_bf16(pf, vf, oacc[ot], 0, 0, 0);
      }
    }
  }
#pragma unroll
  for (int r = 0; r < 4; ++r) l_i[r] = 1.0f / l_i[r];
  u16* ob = out + ((size_t)b * SS + q0 + w * 16 + quad * 4) * DD + h * HD;
#pragma unroll
  for (int ot = 0; ot < 8; ++ot)
#pragma unroll
    for (int r = 0; r < 4; ++r)
      ob[(size_t)r * DD + ot * 16 + col] = f2b(oacc[ot][r] * l_i[r]);
}

extern "C" void kernel_launch(void* const* d_in, const int* in_sizes, int n_in,
                              void* d_out, int out_size, void* d_ws, size_t ws_size,
                              hipStream_t stream) {
  const float* x    = (const float*)d_in[0];
  const float* ln1w = (const float*)d_in[1];
  const float* ln1b = (const float*)d_in[2];
  const float* wqkv = (const float*)d_in[3];
  const float* bqkv = (const float*)d_in[4];
  const float* wo   = (const float*)d_in[5];
  const float* bo   = (const float*)d_in[6];
  const float* ln2w = (const float*)d_in[7];
  const float* ln2b = (const float*)d_in[8];
  const float* w1   = (const float*)d_in[9];
  const float* b1   = (const float*)d_in[10];
  const float* w2   = (const float*)d_in[11];
  const float* b2   = (const float*)d_in[12];

  const int M = BB * SS;  // 4096
  // workspace arena (~185 MB): wt | qkv(+h2) | cbuf(h1/attn/m1) | r1
  char* ws = (char*)d_ws;
  u16*  wt   = (u16*)ws;                                          // 33.55 MB max
  u16*  qkv  = (u16*)(ws + 33554432ull);                          // 50.33 MB
  u16*  cbuf = (u16*)(ws + 33554432ull + 50331648ull);            // 67.11 MB
  float* r1  = (float*)(ws + 33554432ull + 50331648ull + 67108864ull);  // 33.55 MB
  u16* h1 = cbuf;     // dead after QKV gemm
  u16* attn = cbuf;   // written by attention, dead after proj gemm
  u16* m1 = cbuf;     // MLP hidden
  u16* h2 = qkv;      // reuse qkv slot after attention

  ln_kernel<<<M, 256, 0, stream>>>(x, ln1w, ln1b, h1);
  wconv_t<<<dim3(DD / 64, TD / 64), 256, 0, stream>>>(wqkv, wt, DD, TD);
  gemm_bt<0><<<dim3(TD / 128, M / 128), 256, 0, stream>>>(h1, wt, bqkv, nullptr, qkv, M, TD, DD);
  attn_kernel<<<dim3(SS / 64, HH, BB), 256, 0, stream>>>(qkv, attn);
  wconv_t<<<dim3(DD / 64, DD / 64), 256, 0, stream>>>(wo, wt, DD, DD);
  gemm_bt<2><<<dim3(DD / 128, M / 128), 256, 0, stream>>>(attn, wt, bo, x, r1, M, DD, DD);
  ln_kernel<<<M, 256, 0, stream>>>(r1, ln2w, ln2b, h2);
  wconv_t<<<dim3(DD / 64, FFD / 64), 256, 0, stream>>>(w1, wt, DD, FFD);
  gemm_bt<1><<<dim3(FFD / 128, M / 128), 256, 0, stream>>>(h2, wt, b1, nullptr, m1, M, FFD, DD);
  wconv_t<<<dim3(FFD / 64, DD / 64), 256, 0, stream>>>(w2, wt, FFD, DD);
  gemm_bt<2><<<dim3(DD / 128, M / 128), 256, 0, stream>>>(m1, wt, b2, r1, (float*)d_out, M, DD, FFD);
}

// Round 2
// 1027.944 us; speedup vs baseline: 1.3172x; 1.3172x over previous
//
#include <hip/hip_runtime.h>
#include <hip/hip_bf16.h>
#include <stdint.h>

#define BB 2
#define SS 2048
#define DD 2048
#define HH 16
#define HD 128
#define FFD 8192
#define TD (3*DD)

typedef unsigned short u16;
typedef __attribute__((ext_vector_type(8))) short s16x8;
typedef __attribute__((ext_vector_type(4))) float f32x4;

struct alignas(8) U16x4 { u16 a, b, c, d; };

__device__ __forceinline__ u16 f2b(float f) {
  union { float f; uint32_t u; } v; v.f = f;
  uint32_t r = (v.u + 0x7fffu + ((v.u >> 16) & 1u)) >> 16;
  return (u16)r;
}

__device__ __forceinline__ void async16(const void* g, void* l) {
  __builtin_amdgcn_global_load_lds((const __attribute__((address_space(1))) void*)g,
                                   (__attribute__((address_space(3))) void*)l,
                                   16, 0, 0);
}

// ---------------- fused fp32->bf16 transpose-convert:  Wt[N][K] = bf16(W[K][N]) ---
__global__ __launch_bounds__(256) void wconv_t(const float* __restrict__ W,
                                               u16* __restrict__ Wt, int K, int N) {
  __shared__ float tile[64][65];
  int k0 = blockIdx.x * 64, n0 = blockIdx.y * 64;
  int c = threadIdx.x & 63, r0 = threadIdx.x >> 6;
#pragma unroll
  for (int i = 0; i < 16; ++i) {
    int r = i * 4 + r0;
    tile[r][c] = W[(size_t)(k0 + r) * N + n0 + c];
  }
  __syncthreads();
#pragma unroll
  for (int i = 0; i < 16; ++i) {
    int n = i * 4 + r0;
    Wt[(size_t)(n0 + n) * K + k0 + c] = f2b(tile[c][n]);
  }
}

// ---------------- layernorm: fp32 in -> bf16 out, one block per row (D=2048) ------
__global__ __launch_bounds__(256) void ln_kernel(const float* __restrict__ X,
                                                 const float* __restrict__ g,
                                                 const float* __restrict__ be,
                                                 u16* __restrict__ O) {
  int row = blockIdx.x;
  const float* xr = X + (size_t)row * DD;
  int t = threadIdx.x;
  float4 v0 = ((const float4*)xr)[t];
  float4 v1 = ((const float4*)xr)[t + 256];
  float s = v0.x + v0.y + v0.z + v0.w + v1.x + v1.y + v1.z + v1.w;
  float q = v0.x*v0.x + v0.y*v0.y + v0.z*v0.z + v0.w*v0.w
          + v1.x*v1.x + v1.y*v1.y + v1.z*v1.z + v1.w*v1.w;
#pragma unroll
  for (int o = 32; o > 0; o >>= 1) { s += __shfl_down(s, o); q += __shfl_down(q, o); }
  __shared__ float red[8];
  if ((t & 63) == 0) { red[t >> 6] = s; red[4 + (t >> 6)] = q; }
  __syncthreads();
  float S = red[0] + red[1] + red[2] + red[3];
  float Q = red[4] + red[5] + red[6] + red[7];
  float mu = S * (1.0f / DD);
  float var = Q * (1.0f / DD) - mu * mu;
  float rs = rsqrtf(var + 1e-5f);
  float4 g0 = ((const float4*)g)[t],  g1 = ((const float4*)g)[t + 256];
  float4 b0 = ((const float4*)be)[t], b1 = ((const float4*)be)[t + 256];
  U16x4 o0, o1;
  o0.a = f2b((v0.x - mu) * rs * g0.x + b0.x);
  o0.b = f2b((v0.y - mu) * rs * g0.y + b0.y);
  o0.c = f2b((v0.z - mu) * rs * g0.z + b0.z);
  o0.d = f2b((v0.w - mu) * rs * g0.w + b0.w);
  o1.a = f2b((v1.x - mu) * rs * g1.x + b1.x);
  o1.b = f2b((v1.y - mu) * rs * g1.y + b1.y);
  o1.c = f2b((v1.z - mu) * rs * g1.z + b1.z);
  o1.d = f2b((v1.w - mu) * rs * g1.w + b1.w);
  *(U16x4*)(O + (size_t)row * DD + t * 4)         = o0;
  *(U16x4*)(O + (size_t)row * DD + (t + 256) * 4) = o1;
}

// ---------------- GEMM: C[M,N] = A[M,K](bf16) * Bt[N,K](bf16)^T + bias (+epilogue) -
// MODE 0: +bias -> bf16 ; MODE 1: +bias,gelu -> bf16 ; MODE 2: +bias,+res -> fp32
template <int MODE>
__global__ __launch_bounds__(256) void gemm_bt(const u16* __restrict__ A,
                                               const u16* __restrict__ Bt,
                                               const float* __restrict__ bias,
                                               const float* __restrict__ res,
                                               void* __restrict__ Cout,
                                               int M, int N, int K) {
  __shared__ __align__(16) u16 As[128 * 64];
  __shared__ __align__(16) u16 Bs[128 * 64];
  int n0 = blockIdx.x * 128, m0 = blockIdx.y * 128;
  int tid = threadIdx.x;
  int lane = tid & 63, w = tid >> 6;
  int wm = w >> 1, wn = w & 1;
  int col = lane & 15, quad = lane >> 4;
  f32x4 acc[4][4] = {};
  const u16* ag = A  + (size_t)(m0 + (tid >> 3)) * K + (tid & 7) * 8;
  const u16* bg = Bt + (size_t)(n0 + (tid >> 3)) * K + (tid & 7) * 8;
  for (int k0 = 0; k0 < K; k0 += 64) {
    __syncthreads();
#pragma unroll
    for (int s = 0; s < 4; ++s) {
      async16(ag + (size_t)s * 32 * K + k0, &As[s * 2048 + tid * 8]);
      async16(bg + (size_t)s * 32 * K + k0, &Bs[s * 2048 + tid * 8]);
    }
    __syncthreads();
#pragma unroll
    for (int kk = 0; kk < 64; kk += 32) {
      s16x8 af[4], bf[4];
#pragma unroll
      for (int mt = 0; mt < 4; ++mt)
        af[mt] = *(const s16x8*)&As[(wm * 64 + mt * 16 + col) * 64 + kk + quad * 8];
#pragma unroll
      for (int nt = 0; nt < 4; ++nt)
        bf[nt] = *(const s16x8*)&Bs[(wn * 64 + nt * 16 + col) * 64 + kk + quad * 8];
#pragma unroll
      for (int mt = 0; mt < 4; ++mt)
#pragma unroll
        for (int nt = 0; nt < 4; ++nt)
          acc[mt][nt] = __builtin_amdgcn_mfma_f32_16x16x32_bf16(af[mt], bf[nt], acc[mt][nt], 0, 0, 0);
    }
  }
#pragma unroll
  for (int mt = 0; mt < 4; ++mt) {
    int mg = m0 + wm * 64 + mt * 16 + quad * 4;
#pragma unroll
    for (int nt = 0; nt < 4; ++nt) {
      int ng = n0 + wn * 64 + nt * 16 + col;
      float bn = bias[ng];
#pragma unroll
      for (int r = 0; r < 4; ++r) {
        float v = acc[mt][nt][r] + bn;
        size_t idx = (size_t)(mg + r) * N + ng;
        if (MODE == 1) {
          float u = 0.7978845608028654f * (v + 0.044715f * v * v * v);
          v = 0.5f * v * (1.0f + tanhf(u));
        }
        if (MODE == 2) {
          ((float*)Cout)[idx] = v + res[idx];
        } else {
          ((u16*)Cout)[idx] = f2b(v);
        }
      }
    }
  }
}

// ---------------- flash attention with ALiBi + causal --------------------------
// grid: (16, H, B); block 256 (4 waves). Block bx handles q-tiles bx and 31-bx
// (uniform 33 K-tiles/block). K double-buffered via global_load_lds; V prefetched
// into registers one tile ahead and written XOR-swizzled (kills 32-way conflicts).
__global__ __launch_bounds__(256) void attn_kernel(const u16* __restrict__ qkv,
                                                   u16* __restrict__ out) {
  __shared__ __align__(16) u16 Ks[2][64 * 128];   // [key][hd], k-contiguous
  __shared__ __align__(16) u16 Vts[128 * 64];     // [hd][key^swz]
  __shared__ __align__(16) u16 Ps[4][16 * 64];
  int bx = blockIdx.x, h = blockIdx.y, b = blockIdx.z;
  int tid = threadIdx.x, lane = tid & 63, w = tid >> 6;
  int col = lane & 15, quad = lane >> 4;
  const u16* base  = qkv + (size_t)b * SS * TD + (size_t)h * HD;
  const u16* kbase = base + DD;
  const u16* vbase = base + 2 * DD;
  float slope = exp2f(-0.5f * (float)(h + 1));
  const float scale = 0.088388347648318447f;  // 1/sqrt(128)
  int vkey_loc = tid >> 4;         // 0..15 within 16-key group
  int vhd0 = (tid & 15) * 8;
  int kxc = 8 * (tid & 7);         // swizzle constant for this thread's hd rows

#pragma unroll 1
  for (int ph = 0; ph < 2; ++ph) {
    int qt = ph ? (31 - bx) : bx;
    int q0 = qt * 64;
    int ntile = qt + 1;
    // Q fragments (A-layout: m = lane&15)
    int qr = q0 + w * 16 + col;
    s16x8 qf[4];
#pragma unroll
    for (int c = 0; c < 4; ++c)
      qf[c] = *(const s16x8*)(base + (size_t)qr * TD + c * 32 + quad * 8);
    float m_i[4] = {-1e30f, -1e30f, -1e30f, -1e30f};
    float l_i[4] = {0.f, 0.f, 0.f, 0.f};
    f32x4 oacc[8] = {};
    // prologue: async K(0) -> Ks[0]; V(0) -> regs
#pragma unroll
    for (int s = 0; s < 4; ++s)
      async16(kbase + (size_t)(s * 16 + (tid >> 4)) * TD + (tid & 15) * 8,
              &Ks[0][s * 2048 + tid * 8]);
    s16x8 vreg[4];
#pragma unroll
    for (int s = 0; s < 4; ++s)
      vreg[s] = *(const s16x8*)(vbase + (size_t)(s * 16 + vkey_loc) * TD + vhd0);

    for (int t = 0; t < ntile; ++t) {
      int j0 = t * 64;
      __syncthreads();   // K(t) async + vreg(t) drained; all waves past tile t-1
      // prefetch K(t+1)
      if (t + 1 < ntile) {
#pragma unroll
        for (int s = 0; s < 4; ++s)
          async16(kbase + (size_t)(j0 + 64 + s * 16 + (tid >> 4)) * TD + (tid & 15) * 8,
                  &Ks[(t + 1) & 1][s * 2048 + tid * 8]);
      }
      // write V(t) from regs, swizzled: Vt[hd][key ^ 8*(tid&7)]
#pragma unroll
      for (int s = 0; s < 4; ++s) {
        int key = s * 16 + vkey_loc;
#pragma unroll
        for (int j = 0; j < 8; ++j)
          Vts[(vhd0 + j) * 64 + (key ^ kxc)] = (u16)vreg[s][j];
      }
      // prefetch V(t+1) into regs
      if (t + 1 < ntile) {
#pragma unroll
        for (int s = 0; s < 4; ++s)
          vreg[s] = *(const s16x8*)(vbase + (size_t)(j0 + 64 + s * 16 + vkey_loc) * TD + vhd0);
      }
      // QK^T from Ks[t&1]
      const u16* kt_ = Ks[t & 1];
      f32x4 sc[4];
#pragma unroll
      for (int nt = 0; nt < 4; ++nt) {
        f32x4 s4 = {0.f, 0.f, 0.f, 0.f};
        int key = nt * 16 + col;
#pragma unroll
        for (int c = 0; c < 4; ++c) {
          s16x8 kf = *(const s16x8*)&kt_[key * 128 + c * 32 + quad * 8];
          s4 = __builtin_amdgcn_mfma_f32_16x16x32_bf16(qf[c], kf, s4, 0, 0, 0);
        }
        sc[nt] = s4;
      }
      // online softmax (C-layout rows: quad*4+r)
      int rb = q0 + w * 16 + quad * 4;
      float p[4][4];
      float mt_[4] = {-1e30f, -1e30f, -1e30f, -1e30f};
#pragma unroll
      for (int nt = 0; nt < 4; ++nt) {
        int j = j0 + nt * 16 + col;
#pragma unroll
        for (int r = 0; r < 4; ++r) {
          float v = sc[nt][r] * scale + slope * (float)(j - (rb + r));
          if (j > rb + r) v = -1e30f;
          p[nt][r] = v;
          mt_[r] = fmaxf(mt_[r], v);
        }
      }
#pragma unroll
      for (int o = 1; o < 16; o <<= 1)
#pragma unroll
        for (int r = 0; r < 4; ++r) mt_[r] = fmaxf(mt_[r], __shfl_xor(mt_[r], o));
      float alpha[4];
#pragma unroll
      for (int r = 0; r < 4; ++r) {
        float mn = fmaxf(m_i[r], mt_[r]);
        alpha[r] = __expf(m_i[r] - mn);
        m_i[r] = mn;
      }
      float ls[4] = {0.f, 0.f, 0.f, 0.f};
#pragma unroll
      for (int nt = 0; nt < 4; ++nt)
#pragma unroll
        for (int r = 0; r < 4; ++r) {
          float e = __expf(p[nt][r] - m_i[r]);
          p[nt][r] = e;
          ls[r] += e;
        }
#pragma unroll
      for (int o = 1; o < 16; o <<= 1)
#pragma unroll
        for (int r = 0; r < 4; ++r) ls[r] += __shfl_xor(ls[r], o);
#pragma unroll
      for (int r = 0; r < 4; ++r) l_i[r] = l_i[r] * alpha[r] + ls[r];
#pragma unroll
      for (int ot = 0; ot < 8; ++ot)
#pragma unroll
        for (int r = 0; r < 4; ++r) oacc[ot][r] *= alpha[r];
      // P -> LDS (wave-private, A-layout source)
#pragma unroll
      for (int nt = 0; nt < 4; ++nt)
#pragma unroll
        for (int r = 0; r < 4; ++r)
          Ps[w][(quad * 4 + r) * 64 + nt * 16 + col] = f2b(p[nt][r]);
      __syncthreads();   // Vts(t) visible to all waves; all waves done QK(t)
      // PV from swizzled Vts
#pragma unroll
      for (int kt = 0; kt < 2; ++kt) {
        s16x8 pf = *(const s16x8*)&Ps[w][col * 64 + kt * 32 + quad * 8];
        int k8 = kt * 32 + quad * 8;
#pragma unroll
        for (int ot = 0; ot < 8; ++ot) {
          int hd = ot * 16 + col;
          int swz = 8 * (((hd >> 3)) & 7);
          s16x8 vf = *(const s16x8*)&Vts[hd * 64 + (k8 ^ swz)];
          oacc[ot] = __builtin_amdgcn_mfma_f32_16x16x32_bf16(pf, vf, oacc[ot], 0, 0, 0);
        }
      }
    }
#pragma unroll
    for (int r = 0; r < 4; ++r) l_i[r] = 1.0f / l_i[r];
    u16* ob = out + ((size_t)b * SS + q0 + w * 16 + quad * 4) * DD + h * HD;
#pragma unroll
    for (int ot = 0; ot < 8; ++ot)
#pragma unroll
      for (int r = 0; r < 4; ++r)
        ob[(size_t)r * DD + ot * 16 + col] = f2b(oacc[ot][r] * l_i[r]);
  }
}

extern "C" void kernel_launch(void* const* d_in, const int* in_sizes, int n_in,
                              void* d_out, int out_size, void* d_ws, size_t ws_size,
                              hipStream_t stream) {
  const float* x    = (const float*)d_in[0];
  const float* ln1w = (const float*)d_in[1];
  const float* ln1b = (const float*)d_in[2];
  const float* wqkv = (const float*)d_in[3];
  const float* bqkv = (const float*)d_in[4];
  const float* wo   = (const float*)d_in[5];
  const float* bo   = (const float*)d_in[6];
  const float* ln2w = (const float*)d_in[7];
  const float* ln2b = (const float*)d_in[8];
  const float* w1   = (const float*)d_in[9];
  const float* b1   = (const float*)d_in[10];
  const float* w2   = (const float*)d_in[11];
  const float* b2   = (const float*)d_in[12];

  const int M = BB * SS;  // 4096
  // workspace arena (~185 MB): wt | qkv(+h2) | cbuf(h1/attn/m1) | r1
  char* ws = (char*)d_ws;
  u16*  wt   = (u16*)ws;                                          // 33.55 MB max
  u16*  qkv  = (u16*)(ws + 33554432ull);                          // 50.33 MB
  u16*  cbuf = (u16*)(ws + 33554432ull + 50331648ull);            // 67.11 MB
  float* r1  = (float*)(ws + 33554432ull + 50331648ull + 67108864ull);  // 33.55 MB
  u16* h1 = cbuf;     // dead after QKV gemm
  u16* attn = cbuf;   // written by attention, dead after proj gemm
  u16* m1 = cbuf;     // MLP hidden
  u16* h2 = qkv;      // reuse qkv slot after attention

  ln_kernel<<<M, 256, 0, stream>>>(x, ln1w, ln1b, h1);
  wconv_t<<<dim3(DD / 64, TD / 64), 256, 0, stream>>>(wqkv, wt, DD, TD);
  gemm_bt<0><<<dim3(TD / 128, M / 128), 256, 0, stream>>>(h1, wt, bqkv, nullptr, qkv, M, TD, DD);
  attn_kernel<<<dim3(16, HH, BB), 256, 0, stream>>>(qkv, attn);
  wconv_t<<<dim3(DD / 64, DD / 64), 256, 0, stream>>>(wo, wt, DD, DD);
  gemm_bt<2><<<dim3(DD / 128, M / 128), 256, 0, stream>>>(attn, wt, bo, x, r1, M, DD, DD);
  ln_kernel<<<M, 256, 0, stream>>>(r1, ln2w, ln2b, h2);
  wconv_t<<<dim3(DD / 64, FFD / 64), 256, 0, stream>>>(w1, wt, DD, FFD);
  gemm_bt<1><<<dim3(FFD / 128, M / 128), 256, 0, stream>>>(h2, wt, b1, nullptr, m1, M, FFD, DD);
  wconv_t<<<dim3(FFD / 64, DD / 64), 256, 0, stream>>>(w2, wt, FFD, DD);
  gemm_bt<2><<<dim3(DD / 128, M / 128), 256, 0, stream>>>(m1, wt, b2, r1, (float*)d_out, M, DD, FFD);
}

// Round 3
// 887.688 us; speedup vs baseline: 1.5253x; 1.1580x over previous
//
#include <hip/hip_runtime.h>
#include <hip/hip_bf16.h>
#include <stdint.h>

#define BB 2
#define SS 2048
#define DD 2048
#define HH 16
#define HD 128
#define FFD 8192
#define TD (3*DD)

typedef unsigned short u16;
typedef __attribute__((ext_vector_type(8))) short s16x8;
typedef __attribute__((ext_vector_type(4))) float f32x4;

struct alignas(8) U16x4 { u16 a, b, c, d; };

__device__ __forceinline__ u16 f2b(float f) {
  union { float f; uint32_t u; } v; v.f = f;
  uint32_t r = (v.u + 0x7fffu + ((v.u >> 16) & 1u)) >> 16;
  return (u16)r;
}

__device__ __forceinline__ void async16(const void* g, void* l) {
  __builtin_amdgcn_global_load_lds((const __attribute__((address_space(1))) void*)g,
                                   (__attribute__((address_space(3))) void*)l,
                                   16, 0, 0);
}

// ---------------- fused fp32->bf16 transpose-convert:  Wt[N][K] = bf16(W[K][N]) ---
__global__ __launch_bounds__(256) void wconv_t(const float* __restrict__ W,
                                               u16* __restrict__ Wt, int K, int N) {
  __shared__ float tile[64][65];
  int k0 = blockIdx.x * 64, n0 = blockIdx.y * 64;
  int c = threadIdx.x & 63, r0 = threadIdx.x >> 6;
#pragma unroll
  for (int i = 0; i < 16; ++i) {
    int r = i * 4 + r0;
    tile[r][c] = W[(size_t)(k0 + r) * N + n0 + c];
  }
  __syncthreads();
#pragma unroll
  for (int i = 0; i < 16; ++i) {
    int n = i * 4 + r0;
    Wt[(size_t)(n0 + n) * K + k0 + c] = f2b(tile[c][n]);
  }
}

// ---------------- layernorm: fp32 in -> bf16 out, one block per row (D=2048) ------
__global__ __launch_bounds__(256) void ln_kernel(const float* __restrict__ X,
                                                 const float* __restrict__ g,
                                                 const float* __restrict__ be,
                                                 u16* __restrict__ O) {
  int row = blockIdx.x;
  const float* xr = X + (size_t)row * DD;
  int t = threadIdx.x;
  float4 v0 = ((const float4*)xr)[t];
  float4 v1 = ((const float4*)xr)[t + 256];
  float s = v0.x + v0.y + v0.z + v0.w + v1.x + v1.y + v1.z + v1.w;
  float q = v0.x*v0.x + v0.y*v0.y + v0.z*v0.z + v0.w*v0.w
          + v1.x*v1.x + v1.y*v1.y + v1.z*v1.z + v1.w*v1.w;
#pragma unroll
  for (int o = 32; o > 0; o >>= 1) { s += __shfl_down(s, o); q += __shfl_down(q, o); }
  __shared__ float red[8];
  if ((t & 63) == 0) { red[t >> 6] = s; red[4 + (t >> 6)] = q; }
  __syncthreads();
  float S = red[0] + red[1] + red[2] + red[3];
  float Q = red[4] + red[5] + red[6] + red[7];
  float mu = S * (1.0f / DD);
  float var = Q * (1.0f / DD) - mu * mu;
  float rs = rsqrtf(var + 1e-5f);
  float4 g0 = ((const float4*)g)[t],  g1 = ((const float4*)g)[t + 256];
  float4 b0 = ((const float4*)be)[t], b1 = ((const float4*)be)[t + 256];
  U16x4 o0, o1;
  o0.a = f2b((v0.x - mu) * rs * g0.x + b0.x);
  o0.b = f2b((v0.y - mu) * rs * g0.y + b0.y);
  o0.c = f2b((v0.z - mu) * rs * g0.z + b0.z);
  o0.d = f2b((v0.w - mu) * rs * g0.w + b0.w);
  o1.a = f2b((v1.x - mu) * rs * g1.x + b1.x);
  o1.b = f2b((v1.y - mu) * rs * g1.y + b1.y);
  o1.c = f2b((v1.z - mu) * rs * g1.z + b1.z);
  o1.d = f2b((v1.w - mu) * rs * g1.w + b1.w);
  *(U16x4*)(O + (size_t)row * DD + t * 4)         = o0;
  *(U16x4*)(O + (size_t)row * DD + (t + 256) * 4) = o1;
}

// ---------------- GEMM: C[M,N] = A[M,K](bf16) * Bt[N,K](bf16)^T + bias (+epilogue) -
// LDS layout XOR-swizzled: row r, slot s (8 u16 each) holds global k-block s^(r&7).
// Staging keeps LDS dest = base+lane*16 (global_load_lds constraint); the GLOBAL
// address is permuted instead (stays within the same 128B segment -> coalesced).
// MODE 0: +bias -> bf16 ; MODE 1: +bias,gelu -> bf16 ; MODE 2: +bias,+res -> fp32
template <int MODE>
__global__ __launch_bounds__(256) void gemm_bt(const u16* __restrict__ A,
                                               const u16* __restrict__ Bt,
                                               const float* __restrict__ bias,
                                               const float* __restrict__ res,
                                               void* __restrict__ Cout,
                                               int M, int N, int K) {
  __shared__ __align__(16) u16 As[128 * 64];
  __shared__ __align__(16) u16 Bs[128 * 64];
  int n0 = blockIdx.x * 128, m0 = blockIdx.y * 128;
  int tid = threadIdx.x;
  int lane = tid & 63, w = tid >> 6;
  int wm = w >> 1, wn = w & 1;
  int col = lane & 15, quad = lane >> 4;
  f32x4 acc[4][4] = {};
  int arow = tid >> 3;
  int gkb = (tid & 7) ^ (arow & 7);      // swizzled global k-block for this lane
  const u16* ag = A  + (size_t)(m0 + arow) * K + gkb * 8;
  const u16* bg = Bt + (size_t)(n0 + arow) * K + gkb * 8;
  int sw = col & 7;                      // read-side swizzle key (row&7 == col&7)
  for (int k0 = 0; k0 < K; k0 += 64) {
    __syncthreads();
#pragma unroll
    for (int s = 0; s < 4; ++s) {
      async16(ag + (size_t)s * 32 * K + k0, &As[s * 2048 + tid * 8]);
      async16(bg + (size_t)s * 32 * K + k0, &Bs[s * 2048 + tid * 8]);
    }
    __syncthreads();
#pragma unroll
    for (int kk = 0; kk < 64; kk += 32) {
      int kb = (kk >> 3) + quad;         // global k-block wanted
      int slot = (kb ^ sw) * 8;
      s16x8 af[4], bf[4];
#pragma unroll
      for (int mt = 0; mt < 4; ++mt)
        af[mt] = *(const s16x8*)&As[(wm * 64 + mt * 16 + col) * 64 + slot];
#pragma unroll
      for (int nt = 0; nt < 4; ++nt)
        bf[nt] = *(const s16x8*)&Bs[(wn * 64 + nt * 16 + col) * 64 + slot];
#pragma unroll
      for (int mt = 0; mt < 4; ++mt)
#pragma unroll
        for (int nt = 0; nt < 4; ++nt)
          acc[mt][nt] = __builtin_amdgcn_mfma_f32_16x16x32_bf16(af[mt], bf[nt], acc[mt][nt], 0, 0, 0);
    }
  }
#pragma unroll
  for (int mt = 0; mt < 4; ++mt) {
    int mg = m0 + wm * 64 + mt * 16 + quad * 4;
#pragma unroll
    for (int nt = 0; nt < 4; ++nt) {
      int ng = n0 + wn * 64 + nt * 16 + col;
      float bn = bias[ng];
#pragma unroll
      for (int r = 0; r < 4; ++r) {
        float v = acc[mt][nt][r] + bn;
        size_t idx = (size_t)(mg + r) * N + ng;
        if (MODE == 1) {
          // gelu(v) = v * sigmoid(2*0.7978845608*(v + 0.044715 v^3))
          float u = 1.5957691216057308f * (v + 0.044715f * v * v * v);
          v = v / (1.0f + __expf(-u));
        }
        if (MODE == 2) {
          ((float*)Cout)[idx] = v + res[idx];
        } else {
          ((u16*)Cout)[idx] = f2b(v);
        }
      }
    }
  }
}

// ---------------- flash attention with ALiBi + causal --------------------------
// grid: (16, H, B); block 256 (4 waves). Block bx handles q-tiles bx and 31-bx.
// K double-buffered via global_load_lds with XOR-swizzled hd-blocks; V prefetched
// into regs one tile ahead, written XOR-swizzled; Ps padded to stride 72.
__global__ __launch_bounds__(256) void attn_kernel(const u16* __restrict__ qkv,
                                                   u16* __restrict__ out) {
  __shared__ __align__(16) u16 Ks[2][64 * 128];   // [key][hd-slot^swz]
  __shared__ __align__(16) u16 Vts[128 * 64];     // [hd][key^swz]
  __shared__ __align__(16) u16 Ps[4][16 * 72];    // padded stride 72 (144B, 16B-aligned)
  int bx = blockIdx.x, h = blockIdx.y, b = blockIdx.z;
  int tid = threadIdx.x, lane = tid & 63, w = tid >> 6;
  int col = lane & 15, quad = lane >> 4;
  const u16* base  = qkv + (size_t)b * SS * TD + (size_t)h * HD;
  const u16* kbase = base + DD;
  const u16* vbase = base + 2 * DD;
  float slope = exp2f(-0.5f * (float)(h + 1));
  const float scale = 0.088388347648318447f;  // 1/sqrt(128)
  int krow = tid >> 4;                       // key within 16-key staging group
  int ghb = (tid & 15) ^ (krow & 7);         // swizzled global hd-block for K staging
  int vkey_loc = tid >> 4;
  int vhd0 = (tid & 15) * 8;
  int kxc = 8 * (tid & 7);                   // V write swizzle

#pragma unroll 1
  for (int ph = 0; ph < 2; ++ph) {
    int qt = ph ? (31 - bx) : bx;
    int q0 = qt * 64;
    int ntile = qt + 1;
    int qr = q0 + w * 16 + col;
    s16x8 qf[4];
#pragma unroll
    for (int c = 0; c < 4; ++c)
      qf[c] = *(const s16x8*)(base + (size_t)qr * TD + c * 32 + quad * 8);
    float m_i[4] = {-1e30f, -1e30f, -1e30f, -1e30f};
    float l_i[4] = {0.f, 0.f, 0.f, 0.f};
    f32x4 oacc[8] = {};
#pragma unroll
    for (int s = 0; s < 4; ++s)
      async16(kbase + (size_t)(s * 16 + krow) * TD + ghb * 8,
              &Ks[0][s * 2048 + tid * 8]);
    s16x8 vreg[4];
#pragma unroll
    for (int s = 0; s < 4; ++s)
      vreg[s] = *(const s16x8*)(vbase + (size_t)(s * 16 + vkey_loc) * TD + vhd0);

    for (int t = 0; t < ntile; ++t) {
      int j0 = t * 64;
      __syncthreads();
      if (t + 1 < ntile) {
#pragma unroll
        for (int s = 0; s < 4; ++s)
          async16(kbase + (size_t)(j0 + 64 + s * 16 + krow) * TD + ghb * 8,
                  &Ks[(t + 1) & 1][s * 2048 + tid * 8]);
      }
#pragma unroll
      for (int s = 0; s < 4; ++s) {
        int key = s * 16 + vkey_loc;
#pragma unroll
        for (int j = 0; j < 8; ++j)
          Vts[(vhd0 + j) * 64 + (key ^ kxc)] = (u16)vreg[s][j];
      }
      if (t + 1 < ntile) {
#pragma unroll
        for (int s = 0; s < 4; ++s)
          vreg[s] = *(const s16x8*)(vbase + (size_t)(j0 + 64 + s * 16 + vkey_loc) * TD + vhd0);
      }
      const u16* kt_ = Ks[t & 1];
      f32x4 sc[4];
#pragma unroll
      for (int nt = 0; nt < 4; ++nt) {
        f32x4 s4 = {0.f, 0.f, 0.f, 0.f};
        int key = nt * 16 + col;
        int ksw = col & 7;                 // key&7 == col&7
#pragma unroll
        for (int c = 0; c < 4; ++c) {
          s16x8 kf = *(const s16x8*)&kt_[key * 128 + (((c * 4 + quad) ^ ksw) * 8)];
          s4 = __builtin_amdgcn_mfma_f32_16x16x32_bf16(qf[c], kf, s4, 0, 0, 0);
        }
        sc[nt] = s4;
      }
      int rb = q0 + w * 16 + quad * 4;
      float p[4][4];
      float mt_[4] = {-1e30f, -1e30f, -1e30f, -1e30f};
#pragma unroll
      for (int nt = 0; nt < 4; ++nt) {
        int j = j0 + nt * 16 + col;
#pragma unroll
        for (int r = 0; r < 4; ++r) {
          float v = sc[nt][r] * scale + slope * (float)(j - (rb + r));
          if (j > rb + r) v = -1e30f;
          p[nt][r] = v;
          mt_[r] = fmaxf(mt_[r], v);
        }
      }
#pragma unroll
      for (int o = 1; o < 16; o <<= 1)
#pragma unroll
        for (int r = 0; r < 4; ++r) mt_[r] = fmaxf(mt_[r], __shfl_xor(mt_[r], o));
      float alpha[4];
#pragma unroll
      for (int r = 0; r < 4; ++r) {
        float mn = fmaxf(m_i[r], mt_[r]);
        alpha[r] = __expf(m_i[r] - mn);
        m_i[r] = mn;
      }
      float ls[4] = {0.f, 0.f, 0.f, 0.f};
#pragma unroll
      for (int nt = 0; nt < 4; ++nt)
#pragma unroll
        for (int r = 0; r < 4; ++r) {
          float e = __expf(p[nt][r] - m_i[r]);
          p[nt][r] = e;
          ls[r] += e;
        }
#pragma unroll
      for (int o = 1; o < 16; o <<= 1)
#pragma unroll
        for (int r = 0; r < 4; ++r) ls[r] += __shfl_xor(ls[r], o);
#pragma unroll
      for (int r = 0; r < 4; ++r) l_i[r] = l_i[r] * alpha[r] + ls[r];
#pragma unroll
      for (int ot = 0; ot < 8; ++ot)
#pragma unroll
        for (int r = 0; r < 4; ++r) oacc[ot][r] *= alpha[r];
#pragma unroll
      for (int nt = 0; nt < 4; ++nt)
#pragma unroll
        for (int r = 0; r < 4; ++r)
          Ps[w][(quad * 4 + r) * 72 + nt * 16 + col] = f2b(p[nt][r]);
      __syncthreads();
#pragma unroll
      for (int kt = 0; kt < 2; ++kt) {
        s16x8 pf = *(const s16x8*)&Ps[w][col * 72 + kt * 32 + quad * 8];
        int k8 = kt * 32 + quad * 8;
#pragma unroll
        for (int ot = 0; ot < 8; ++ot) {
          int hd = ot * 16 + col;
          int swz = 8 * ((hd >> 3) & 7);
          s16x8 vf = *(const s16x8*)&Vts[hd * 64 + (k8 ^ swz)];
          oacc[ot] = __builtin_amdgcn_mfma_f32_16x16x32_bf16(pf, vf, oacc[ot], 0, 0, 0);
        }
      }
    }
#pragma unroll
    for (int r = 0; r < 4; ++r) l_i[r] = 1.0f / l_i[r];
    u16* ob = out + ((size_t)b * SS + q0 + w * 16 + quad * 4) * DD + h * HD;
#pragma unroll
    for (int ot = 0; ot < 8; ++ot)
#pragma unroll
      for (int r = 0; r < 4; ++r)
        ob[(size_t)r * DD + ot * 16 + col] = f2b(oacc[ot][r] * l_i[r]);
  }
}

extern "C" void kernel_launch(void* const* d_in, const int* in_sizes, int n_in,
                              void* d_out, int out_size, void* d_ws, size_t ws_size,
                              hipStream_t stream) {
  const float* x    = (const float*)d_in[0];
  const float* ln1w = (const float*)d_in[1];
  const float* ln1b = (const float*)d_in[2];
  const float* wqkv = (const float*)d_in[3];
  const float* bqkv = (const float*)d_in[4];
  const float* wo   = (const float*)d_in[5];
  const float* bo   = (const float*)d_in[6];
  const float* ln2w = (const float*)d_in[7];
  const float* ln2b = (const float*)d_in[8];
  const float* w1   = (const float*)d_in[9];
  const float* b1   = (const float*)d_in[10];
  const float* w2   = (const float*)d_in[11];
  const float* b2   = (const float*)d_in[12];

  const int M = BB * SS;  // 4096
  char* ws = (char*)d_ws;
  u16*  wt   = (u16*)ws;                                          // 33.55 MB max
  u16*  qkv  = (u16*)(ws + 33554432ull);                          // 50.33 MB
  u16*  cbuf = (u16*)(ws + 33554432ull + 50331648ull);            // 67.11 MB
  float* r1  = (float*)(ws + 33554432ull + 50331648ull + 67108864ull);  // 33.55 MB
  u16* h1 = cbuf;
  u16* attn = cbuf;
  u16* m1 = cbuf;
  u16* h2 = qkv;

  ln_kernel<<<M, 256, 0, stream>>>(x, ln1w, ln1b, h1);
  wconv_t<<<dim3(DD / 64, TD / 64), 256, 0, stream>>>(wqkv, wt, DD, TD);
  gemm_bt<0><<<dim3(TD / 128, M / 128), 256, 0, stream>>>(h1, wt, bqkv, nullptr, qkv, M, TD, DD);
  attn_kernel<<<dim3(16, HH, BB), 256, 0, stream>>>(qkv, attn);
  wconv_t<<<dim3(DD / 64, DD / 64), 256, 0, stream>>>(wo, wt, DD, DD);
  gemm_bt<2><<<dim3(DD / 128, M / 128), 256, 0, stream>>>(attn, wt, bo, x, r1, M, DD, DD);
  ln_kernel<<<M, 256, 0, stream>>>(r1, ln2w, ln2b, h2);
  wconv_t<<<dim3(DD / 64, FFD / 64), 256, 0, stream>>>(w1, wt, DD, FFD);
  gemm_bt<1><<<dim3(FFD / 128, M / 128), 256, 0, stream>>>(h2, wt, b1, nullptr, m1, M, FFD, DD);
  wconv_t<<<dim3(FFD / 64, DD / 64), 256, 0, stream>>>(w2, wt, FFD, DD);
  gemm_bt<2><<<dim3(DD / 128, M / 128), 256, 0, stream>>>(m1, wt, b2, r1, (float*)d_out, M, DD, FFD);
}